// Round 10
// baseline (116.609 us; speedup 1.0000x reference)
//
#include <hip/hip_runtime.h>
#include <math.h>

#define T_TOK 4096
#define DD 64
#define NHEADS 64          // B*H = 4*16
#define SEG 512            // tokens per landmark segment
#define SCALE 0.125f

// workspace layout (in floats)
#define QL_OFF   0                      // [64][8][64]
#define KL_OFF   32768                  // [64][8][64]
#define K2_OFF   65536                  // [64][8][8]
#define CS_OFF   69632                  // [64][8]
#define KP_OFF   70144                  // [4096][64]   k landmark partials (per 64-tok wave)
#define PA_OFF   332288                 // [4096][8][64] k3v partials (per 64-tok wave)
#define PD_OFF   2429440                // [4096][8]    denominators
#define W2_OFF   2462208                // [64][8][64]  pinv @ k3v
// end = 2494976 floats ~= 9.98 MB (<= proven ws size)

#define WAVE_BAR() __builtin_amdgcn_wave_barrier()

// ---------------------------------------------------------------------------
// 1. q landmarks: one block per (head, landmark) 512-token segment (512 blocks).
//    Register double-buffered 8-load batches; writes q_l directly.
// ---------------------------------------------------------------------------
__global__ __launch_bounds__(256) void qsum_kernel(
    const float* __restrict__ q, float* __restrict__ ws) {
  int tid = threadIdx.x;
  const float4* q4 = (const float4*)q + (size_t)blockIdx.x * 8192;
  float4 b[2][8];
#pragma unroll
  for (int i = 0; i < 8; ++i) b[0][i] = q4[i * 256 + tid];
  float4 a = make_float4(0.f, 0.f, 0.f, 0.f);
#pragma unroll
  for (int j = 0; j < 4; ++j) {
    if (j < 3) {
#pragma unroll
      for (int i = 0; i < 8; ++i)
        b[(j + 1) & 1][i] = q4[(j + 1) * 2048 + i * 256 + tid];
    }
#pragma unroll
    for (int i = 0; i < 8; ++i) {
      float4 x = b[j & 1][i];
      a.x += x.x; a.y += x.y; a.z += x.z; a.w += x.w;
    }
  }
  __shared__ float4 red[16][17];
  red[tid >> 4][tid & 15] = a;
  __syncthreads();
  if (tid < 16) {
    float4 s = make_float4(0.f, 0.f, 0.f, 0.f);
#pragma unroll
    for (int g = 0; g < 16; ++g) {
      float4 r = red[g][tid];
      s.x += r.x; s.y += r.y; s.z += r.z; s.w += r.w;
    }
    const float inv = 1.f / (float)SEG;
    s.x *= inv; s.y *= inv; s.z *= inv; s.w *= inv;
    ((float4*)(ws + QL_OFF))[blockIdx.x * 16 + tid] = s;   // q_l directly
  }
}

// ---------------------------------------------------------------------------
// 2. kvpass (fused): one block per 256 tokens (1024 blocks); wave = 64
//    contiguous tokens = 4 x 16-token tiles.  Per tile: stage k AND v in
//    wave-private LDS (single-buffered regs: stage, then issue next loads),
//    thread-local dots vs block-shared q_l -> p in private LDS, then
//    accumulate p*v with thread = (m-pair x 16-dim slice) looping over the
//    tile's tokens from LDS -> only 2 float4 accumulators, no epilogue
//    shuffle for PA.  p never touches global memory.
// ---------------------------------------------------------------------------
__global__ __launch_bounds__(256) void kvpass_kernel(
    const float* __restrict__ k, const float* __restrict__ v,
    float* __restrict__ ws) {
  int tid = threadIdx.x;
  int w = tid >> 6, lane = tid & 63;
  int gw = blockIdx.x * 4 + w;            // 0..4095, 64 tokens each
  int hb = gw >> 6;
  __shared__ float qls[8][68];
  __shared__ float kt_all[4][16][68];
  __shared__ float vt_all[4][16][68];
  __shared__ float pl_all[4][16][9];
  float (*kt)[68] = kt_all[w];
  float (*vt)[68] = vt_all[w];
  float (*pl)[9]  = pl_all[w];

  if (tid < 128) {
    float4 x = ((const float4*)(ws + QL_OFF))[hb * 128 + tid];
    *(float4*)&qls[tid >> 4][(tid & 15) * 4] = x;
  }
  __syncthreads();   // the only block barrier (q_l staged)

  int m = lane & 7, g = lane >> 4, d4i = lane & 15;
  size_t tokbase = (size_t)gw * 64;
  const float4* k4 = (const float4*)k + tokbase * 16;
  const float4* v4 = (const float4*)v + tokbase * 16;

  float4 kb[4], vb[4];
#pragma unroll
  for (int i = 0; i < 4; ++i) { kb[i] = k4[i * 64 + lane]; vb[i] = v4[i * 64 + lane]; }

  float4 ks = make_float4(0.f, 0.f, 0.f, 0.f);
  float den = 0.f;                        // this thread's m, 2 tokens/tile
  float4 acc0 = make_float4(0.f, 0.f, 0.f, 0.f);  // m = g
  float4 acc1 = make_float4(0.f, 0.f, 0.f, 0.f);  // m = g+4

#pragma unroll
  for (int tile = 0; tile < 4; ++tile) {
    // stage current tile (frees kb/vb), accumulate ksum
#pragma unroll
    for (int i = 0; i < 4; ++i) {
      int f4 = i * 64 + lane;
      *(float4*)&kt[f4 >> 4][(f4 & 15) * 4] = kb[i];
      *(float4*)&vt[f4 >> 4][(f4 & 15) * 4] = vb[i];
      ks.x += kb[i].x; ks.y += kb[i].y; ks.z += kb[i].z; ks.w += kb[i].w;
    }
    // issue next tile loads (land during dots+accumulate)
    if (tile < 3) {
#pragma unroll
      for (int i = 0; i < 4; ++i) {
        kb[i] = k4[(tile + 1) * 256 + i * 64 + lane];
        vb[i] = v4[(tile + 1) * 256 + i * 64 + lane];
      }
    }
    WAVE_BAR();
    // dots: thread (t = rep*8 + lane>>3, m = lane&7); conflict-free rows
#pragma unroll
    for (int rep = 0; rep < 2; ++rep) {
      int t = rep * 8 + (lane >> 3);
      const float4* kr = (const float4*)&kt[t][0];
      const float4* qr = (const float4*)&qls[m][0];
      float dp = 0.f;
#pragma unroll
      for (int d4 = 0; d4 < 16; ++d4) {
        float4 kv = kr[d4], qv = qr[d4];
        dp += kv.x * qv.x + kv.y * qv.y + kv.z * qv.z + kv.w * qv.w;
      }
      float p = __expf(dp * SCALE);
      pl[t][m] = p;
      den += p;
    }
    WAVE_BAR();
    // accumulate: thread owns m in {g, g+4}, dims d4i*4..+3; loop tokens
#pragma unroll
    for (int t = 0; t < 16; ++t) {
      float4 vv = *(const float4*)&vt[t][d4i * 4];
      float pa = pl[t][g];
      float pb = pl[t][g + 4];
      acc0.x += pa * vv.x; acc0.y += pa * vv.y; acc0.z += pa * vv.z; acc0.w += pa * vv.w;
      acc1.x += pb * vv.x; acc1.y += pb * vv.y; acc1.z += pb * vv.z; acc1.w += pb * vv.w;
    }
    WAVE_BAR();
  }
  // ksum: reduce over the 4 16-lane groups -> lanes 0..15
  ks.x += __shfl_xor(ks.x, 16, 64); ks.y += __shfl_xor(ks.y, 16, 64);
  ks.z += __shfl_xor(ks.z, 16, 64); ks.w += __shfl_xor(ks.w, 16, 64);
  ks.x += __shfl_xor(ks.x, 32, 64); ks.y += __shfl_xor(ks.y, 32, 64);
  ks.z += __shfl_xor(ks.z, 32, 64); ks.w += __shfl_xor(ks.w, 32, 64);
  if (lane < 16)
    ((float4*)(ws + KP_OFF))[gw * 16 + lane] = ks;
  // den: sum lanes with equal m (stride-8 groups)
  den += __shfl_xor(den, 8, 64);
  den += __shfl_xor(den, 16, 64);
  den += __shfl_xor(den, 32, 64);
  if (lane < 8)
    ws[PD_OFF + (size_t)gw * 8 + lane] = den;
  // PA: each thread owns (g, d4i) and (g+4, d4i) completely — direct store
  ((float4*)(ws + PA_OFF))[((size_t)gw * 8 + g) * 16 + d4i] = acc0;
  ((float4*)(ws + PA_OFF))[((size_t)gw * 8 + g + 4) * 16 + d4i] = acc1;
}

// ---------------------------------------------------------------------------
// 3. Reduce k partials -> k_l; kernel_2 softmax + column sums.
// ---------------------------------------------------------------------------
__global__ __launch_bounds__(512) void prepk_kernel(float* __restrict__ ws) {
  int hb = blockIdx.x, tid = threadIdx.x;
  __shared__ float qls[8][68];
  __shared__ float kls[8][68];
  __shared__ float ee[8][9];
  int m = tid >> 6, d = tid & 63;
  float s = 0.f;
#pragma unroll
  for (int j = 0; j < 8; ++j)
    s += ws[KP_OFF + (size_t)(hb * 64 + m * 8 + j) * 64 + d];
  s *= (1.f / (float)SEG);
  kls[m][d] = s;
  ws[KL_OFF + hb * 512 + tid] = s;
  qls[m][d] = ws[QL_OFF + hb * 512 + tid];
  __syncthreads();
  if (tid < 64) {
    int i = tid >> 3, j = tid & 7;
    float dot = 0.f;
#pragma unroll
    for (int dd = 0; dd < 64; ++dd) dot += qls[i][dd] * kls[j][dd];
    ee[i][j] = __expf(dot * SCALE);   // logits tiny: shift-free softmax safe
  }
  __syncthreads();
  if (tid < 64) {
    int i = tid >> 3, j = tid & 7;
    float ssum = 0.f;
#pragma unroll
    for (int jj = 0; jj < 8; ++jj) ssum += ee[i][jj];
    ws[K2_OFF + hb * 64 + tid] = ee[i][j] / ssum;
  }
  if (tid < 8) {
    float cs = 0.f;
    for (int ii = 0; ii < 8; ++ii) {
      float ssum = 0.f;
#pragma unroll
      for (int jj = 0; jj < 8; ++jj) ssum += ee[ii][jj];
      cs += ee[ii][tid] / ssum;
    }
    ws[CS_OFF + hb * 8 + tid] = cs;
  }
}

// ---------------------------------------------------------------------------
// 4. pinv (Newton-Schulz, global max over all 512 colsums) fused with
//    k3v reduce + W2 = pinv @ (k3v/den).  One 512-thr block per head.
// ---------------------------------------------------------------------------
__global__ __launch_bounds__(512) void pinvw2_kernel(float* __restrict__ ws) {
  int hb = blockIdx.x, tid = threadIdx.x;
  __shared__ float k3vs[8][68];
  __shared__ float K[8][9], V[8][9], X[8][9], Y[8][9];
  __shared__ float smax;
  int m = tid >> 6, d = tid & 63;
  float s = 0.f, den = 0.f;
  for (int c = 0; c < 64; ++c) {
    s += ws[PA_OFF + (((size_t)hb * 64 + c) * 8 + m) * 64 + d];
    den += ws[PD_OFF + ((size_t)hb * 64 + c) * 8 + m];
  }
  k3vs[m][d] = s / den;
  if (tid < 64) {
    float mx = 0.f;
    for (int t = 0; t < 8; ++t) mx = fmaxf(mx, ws[CS_OFF + t * 64 + tid]);
    for (int off = 32; off; off >>= 1) mx = fmaxf(mx, __shfl_xor(mx, off, 64));
    if (tid == 0) smax = mx;
  }
  int i = (tid >> 3) & 7, j = tid & 7;
  if (tid < 64) K[i][j] = ws[K2_OFF + hb * 64 + tid];
  __syncthreads();
  if (tid < 64) V[i][j] = K[j][i] * (1.f / smax);   // (1/max) * K^T
  __syncthreads();
  for (int it = 0; it < 6; ++it) {
    float x = 0.f;
    if (tid < 64) {
      for (int kk = 0; kk < 8; ++kk) x += K[i][kk] * V[kk][j];
      X[i][j] = x;
    }
    __syncthreads();
    float bm = 0.f;
    if (tid < 64) {
      for (int kk = 0; kk < 8; ++kk) bm += X[i][kk] * X[kk][j];
      bm = 7.f * x - bm;
      Y[i][j] = bm;
    }
    __syncthreads();
    float dm = 0.f;
    if (tid < 64) {
      for (int kk = 0; kk < 8; ++kk) dm += X[i][kk] * Y[kk][j];
      dm = 15.f * x - dm;
    }
    __syncthreads();
    if (tid < 64) Y[i][j] = dm;
    __syncthreads();
    float vd = 0.f;
    if (tid < 64) {
      for (int kk = 0; kk < 8; ++kk) vd += V[i][kk] * Y[kk][j];
      vd = 0.25f * (13.f * V[i][j] - vd);
    }
    __syncthreads();
    if (tid < 64) V[i][j] = vd;
    __syncthreads();
  }
  float o = 0.f;
#pragma unroll
  for (int jj = 0; jj < 8; ++jj) o += V[m][jj] * k3vs[jj][d];
  ws[W2_OFF + hb * 512 + tid] = o;
}

// ---------------------------------------------------------------------------
// 5. Output: barrier-free wave-private streaming.  Wave = 64 contiguous
//    tokens (4 x 16-token tiles).  klrow in VGPRs; W2 in private LDS.
//    p = exp(q.k_l*scale); out = (p/Σp) @ W2.  1 KB coalesced stores.
// ---------------------------------------------------------------------------
__global__ __launch_bounds__(256) void out_kernel(
    const float* __restrict__ q, float* __restrict__ out,
    const float* __restrict__ ws) {
  int tid = threadIdx.x;
  int w = tid >> 6, lane = tid & 63;
  int gw = blockIdx.x * 4 + w;            // 0..4095, 64 tokens each
  int hb = gw >> 6;
  __shared__ float qt_all[4][16][68];
  __shared__ float pl_all[4][16][9];
  __shared__ float w2_all[4][8][68];
  float (*qt)[68] = qt_all[w];
  float (*pl)[9]  = pl_all[w];
  float (*w2)[68] = w2_all[w];

  int m = lane & 7;
  float4 klrow[16];
#pragma unroll
  for (int d4 = 0; d4 < 16; ++d4)
    klrow[d4] = ((const float4*)(ws + KL_OFF))[hb * 128 + m * 16 + d4];
#pragma unroll
  for (int i = 0; i < 2; ++i) {
    int f4 = i * 64 + lane;
    float4 y = ((const float4*)(ws + W2_OFF))[hb * 128 + f4];
    *(float4*)&w2[f4 >> 4][(f4 & 15) * 4] = y;
  }

  size_t base4 = (size_t)gw * 1024;       // 64 tokens x 16 float4
  const float4* q4 = (const float4*)q + base4;
  float4* o4 = (float4*)out + base4;
  float4 buf[2][4];
#pragma unroll
  for (int i = 0; i < 4; ++i) buf[0][i] = q4[i * 64 + lane];

#pragma unroll
  for (int tile = 0; tile < 4; ++tile) {
    int cur = tile & 1;
    if (tile < 3) {
#pragma unroll
      for (int i = 0; i < 4; ++i)
        buf[cur ^ 1][i] = q4[(tile + 1) * 256 + i * 64 + lane];
    }
#pragma unroll
    for (int i = 0; i < 4; ++i) {
      int f4 = i * 64 + lane;
      *(float4*)&qt[f4 >> 4][(f4 & 15) * 4] = buf[cur][i];
    }
    WAVE_BAR();
#pragma unroll
    for (int rep = 0; rep < 2; ++rep) {
      int t = rep * 8 + (lane >> 3);
      const float4* qr = (const float4*)&qt[t][0];
      float dot = 0.f;
#pragma unroll
      for (int d4 = 0; d4 < 16; ++d4) {
        float4 a = qr[d4];
        dot += a.x * klrow[d4].x + a.y * klrow[d4].y +
               a.z * klrow[d4].z + a.w * klrow[d4].w;
      }
      pl[t][m] = __expf(dot * SCALE);     // logits tiny: no max needed
    }
    WAVE_BAR();
#pragma unroll
    for (int i = 0; i < 4; ++i) {
      int t = i * 4 + (lane >> 4);
      int qd = lane & 15;
      float p0 = pl[t][0], p1 = pl[t][1], p2 = pl[t][2], p3 = pl[t][3];
      float p4 = pl[t][4], p5 = pl[t][5], p6 = pl[t][6], p7 = pl[t][7];
      float inv = 1.f / (p0 + p1 + p2 + p3 + p4 + p5 + p6 + p7);
      float4 acc = make_float4(0.f, 0.f, 0.f, 0.f);
      float pm[8] = {p0, p1, p2, p3, p4, p5, p6, p7};
#pragma unroll
      for (int m2 = 0; m2 < 8; ++m2) {
        float wgt = pm[m2] * inv;
        float4 wv = *(const float4*)&w2[m2][qd * 4];
        acc.x += wgt * wv.x; acc.y += wgt * wv.y;
        acc.z += wgt * wv.z; acc.w += wgt * wv.w;
      }
      o4[tile * 256 + i * 64 + lane] = acc;   // 1 KB coalesced store
    }
    WAVE_BAR();
  }
}

// ---------------------------------------------------------------------------
extern "C" void kernel_launch(void* const* d_in, const int* in_sizes, int n_in,
                              void* d_out, int out_size, void* d_ws, size_t ws_size,
                              hipStream_t stream) {
  const float* q = (const float*)d_in[0];
  const float* k = (const float*)d_in[1];
  const float* v = (const float*)d_in[2];
  float* out = (float*)d_out;
  float* ws = (float*)d_ws;

  qsum_kernel<<<512, 256, 0, stream>>>(q, ws);
  kvpass_kernel<<<1024, 256, 0, stream>>>(k, v, ws);
  prepk_kernel<<<NHEADS, 512, 0, stream>>>(ws);
  pinvw2_kernel<<<NHEADS, 512, 0, stream>>>(ws);
  out_kernel<<<1024, 256, 0, stream>>>(q, out, ws);
}

// Round 11
// 83.110 us; speedup vs baseline: 1.4031x; 1.4031x over previous
//
#include <hip/hip_runtime.h>
#include <math.h>

#define T_TOK 4096
#define DD 64
#define NHEADS 64          // B*H = 4*16
#define SEG 512            // tokens per landmark segment
#define SCALE 0.125f

// workspace layout (in floats)
#define QL_OFF   0                      // [64][8][64]
#define KL_OFF   32768                  // [64][8][64]
#define K2_OFF   65536                  // [64][8][8]
#define CS_OFF   69632                  // [64][8]
#define KP_OFF   70144                  // [4096][64]   k landmark partials (per 64-tok wave)
#define PA_OFF   332288                 // [4096][8][64] k3v partials (per 64-tok wave)
#define PD_OFF   2429440                // [4096][8]    denominators
#define W2_OFF   2462208                // [64][8][64]  pinv @ k3v
// end = 2494976 floats ~= 9.98 MB (<= proven ws size)

#define WAVE_BAR() __builtin_amdgcn_wave_barrier()

// ---------------------------------------------------------------------------
// 1. q landmarks: one block per (head, landmark) 512-token segment (512 blocks).
//    Register double-buffered 8-load batches; writes q_l directly.
// ---------------------------------------------------------------------------
__global__ __launch_bounds__(256) void qsum_kernel(
    const float* __restrict__ q, float* __restrict__ ws) {
  int tid = threadIdx.x;
  const float4* q4 = (const float4*)q + (size_t)blockIdx.x * 8192;
  float4 b[2][8];
#pragma unroll
  for (int i = 0; i < 8; ++i) b[0][i] = q4[i * 256 + tid];
  float4 a = make_float4(0.f, 0.f, 0.f, 0.f);
#pragma unroll
  for (int j = 0; j < 4; ++j) {
    if (j < 3) {
#pragma unroll
      for (int i = 0; i < 8; ++i)
        b[(j + 1) & 1][i] = q4[(j + 1) * 2048 + i * 256 + tid];
    }
#pragma unroll
    for (int i = 0; i < 8; ++i) {
      float4 x = b[j & 1][i];
      a.x += x.x; a.y += x.y; a.z += x.z; a.w += x.w;
    }
  }
  __shared__ float4 red[16][17];
  red[tid >> 4][tid & 15] = a;
  __syncthreads();
  if (tid < 16) {
    float4 s = make_float4(0.f, 0.f, 0.f, 0.f);
#pragma unroll
    for (int g = 0; g < 16; ++g) {
      float4 r = red[g][tid];
      s.x += r.x; s.y += r.y; s.z += r.z; s.w += r.w;
    }
    const float inv = 1.f / (float)SEG;
    s.x *= inv; s.y *= inv; s.z *= inv; s.w *= inv;
    ((float4*)(ws + QL_OFF))[blockIdx.x * 16 + tid] = s;   // q_l directly
  }
}

// ---------------------------------------------------------------------------
// 2. kvpass (fused): one block per 256 tokens (1024 blocks); wave = 64
//    contiguous tokens = 4 x 16-token tiles.  NO unroll, NO prefetch —
//    TLP (16 waves/CU at 39 KB LDS) hides latency; keeps VGPR < 90.
//    Per tile: load k+v -> wave-private LDS, thread-local dots vs
//    block-shared q_l -> p in private LDS, accumulate p*v with thread =
//    (m-pair x 16-dim slice).  p never touches global memory.
// ---------------------------------------------------------------------------
__global__ __launch_bounds__(256) void kvpass_kernel(
    const float* __restrict__ k, const float* __restrict__ v,
    float* __restrict__ ws) {
  int tid = threadIdx.x;
  int w = tid >> 6, lane = tid & 63;
  int gw = blockIdx.x * 4 + w;            // 0..4095, 64 tokens each
  int hb = gw >> 6;
  __shared__ float qls[8][68];
  __shared__ float kt_all[4][16][68];
  __shared__ float vt_all[4][16][68];
  __shared__ float pl_all[4][16][9];
  float (*kt)[68] = kt_all[w];
  float (*vt)[68] = vt_all[w];
  float (*pl)[9]  = pl_all[w];

  if (tid < 128) {
    float4 x = ((const float4*)(ws + QL_OFF))[hb * 128 + tid];
    *(float4*)&qls[tid >> 4][(tid & 15) * 4] = x;
  }
  __syncthreads();   // the only block barrier (q_l staged)

  int m = lane & 7, g = lane >> 4, d4i = lane & 15;
  size_t tokbase = (size_t)gw * 64;
  const float4* k4 = (const float4*)k + tokbase * 16;
  const float4* v4 = (const float4*)v + tokbase * 16;

  float4 ks = make_float4(0.f, 0.f, 0.f, 0.f);
  float den = 0.f;
  float4 acc0 = make_float4(0.f, 0.f, 0.f, 0.f);  // m = g
  float4 acc1 = make_float4(0.f, 0.f, 0.f, 0.f);  // m = g+4

#pragma unroll 1
  for (int tile = 0; tile < 4; ++tile) {
    // load + stage this tile (4 k + 4 v float4 per thread)
    float4 k0 = k4[tile * 256 + lane];
    float4 k1 = k4[tile * 256 + 64 + lane];
    float4 k2 = k4[tile * 256 + 128 + lane];
    float4 k3 = k4[tile * 256 + 192 + lane];
    float4 v0 = v4[tile * 256 + lane];
    float4 v1 = v4[tile * 256 + 64 + lane];
    float4 v2 = v4[tile * 256 + 128 + lane];
    float4 v3 = v4[tile * 256 + 192 + lane];
    int r0 = lane >> 4, c0 = (lane & 15) * 4;
    *(float4*)&kt[r0][c0] = k0;      *(float4*)&vt[r0][c0] = v0;
    *(float4*)&kt[r0 + 4][c0] = k1;  *(float4*)&vt[r0 + 4][c0] = v1;
    *(float4*)&kt[r0 + 8][c0] = k2;  *(float4*)&vt[r0 + 8][c0] = v2;
    *(float4*)&kt[r0 + 12][c0] = k3; *(float4*)&vt[r0 + 12][c0] = v3;
    ks.x += k0.x + k1.x + k2.x + k3.x;
    ks.y += k0.y + k1.y + k2.y + k3.y;
    ks.z += k0.z + k1.z + k2.z + k3.z;
    ks.w += k0.w + k1.w + k2.w + k3.w;
    WAVE_BAR();
    // dots: thread (t = rep*8 + lane>>3, m = lane&7); conflict-free rows
#pragma unroll
    for (int rep = 0; rep < 2; ++rep) {
      int t = rep * 8 + (lane >> 3);
      const float4* kr = (const float4*)&kt[t][0];
      const float4* qr = (const float4*)&qls[m][0];
      float dp = 0.f;
#pragma unroll
      for (int d4 = 0; d4 < 16; ++d4) {
        float4 kv = kr[d4], qv = qr[d4];
        dp += kv.x * qv.x + kv.y * qv.y + kv.z * qv.z + kv.w * qv.w;
      }
      float p = __expf(dp * SCALE);
      pl[t][m] = p;
      den += p;
    }
    WAVE_BAR();
    // accumulate: thread owns m in {g, g+4}, dims d4i*4..+3; loop tokens
#pragma unroll
    for (int t = 0; t < 16; ++t) {
      float4 vv = *(const float4*)&vt[t][d4i * 4];
      float pa = pl[t][g];
      float pb = pl[t][g + 4];
      acc0.x += pa * vv.x; acc0.y += pa * vv.y; acc0.z += pa * vv.z; acc0.w += pa * vv.w;
      acc1.x += pb * vv.x; acc1.y += pb * vv.y; acc1.z += pb * vv.z; acc1.w += pb * vv.w;
    }
    WAVE_BAR();
  }
  // ksum: reduce over the 4 16-lane groups -> lanes 0..15
  ks.x += __shfl_xor(ks.x, 16, 64); ks.y += __shfl_xor(ks.y, 16, 64);
  ks.z += __shfl_xor(ks.z, 16, 64); ks.w += __shfl_xor(ks.w, 16, 64);
  ks.x += __shfl_xor(ks.x, 32, 64); ks.y += __shfl_xor(ks.y, 32, 64);
  ks.z += __shfl_xor(ks.z, 32, 64); ks.w += __shfl_xor(ks.w, 32, 64);
  if (lane < 16)
    ((float4*)(ws + KP_OFF))[gw * 16 + lane] = ks;
  // den: sum lanes with equal m (stride-8 groups)
  den += __shfl_xor(den, 8, 64);
  den += __shfl_xor(den, 16, 64);
  den += __shfl_xor(den, 32, 64);
  if (lane < 8)
    ws[PD_OFF + (size_t)gw * 8 + lane] = den;
  // PA: each thread owns (g, d4i) and (g+4, d4i) completely — direct store
  ((float4*)(ws + PA_OFF))[((size_t)gw * 8 + g) * 16 + d4i] = acc0;
  ((float4*)(ws + PA_OFF))[((size_t)gw * 8 + g + 4) * 16 + d4i] = acc1;
}

// ---------------------------------------------------------------------------
// 3. Reduce k partials -> k_l; kernel_2 softmax + column sums.
// ---------------------------------------------------------------------------
__global__ __launch_bounds__(512) void prepk_kernel(float* __restrict__ ws) {
  int hb = blockIdx.x, tid = threadIdx.x;
  __shared__ float qls[8][68];
  __shared__ float kls[8][68];
  __shared__ float ee[8][9];
  int m = tid >> 6, d = tid & 63;
  float s = 0.f;
#pragma unroll
  for (int j = 0; j < 8; ++j)
    s += ws[KP_OFF + (size_t)(hb * 64 + m * 8 + j) * 64 + d];
  s *= (1.f / (float)SEG);
  kls[m][d] = s;
  ws[KL_OFF + hb * 512 + tid] = s;
  qls[m][d] = ws[QL_OFF + hb * 512 + tid];
  __syncthreads();
  if (tid < 64) {
    int i = tid >> 3, j = tid & 7;
    float dot = 0.f;
#pragma unroll
    for (int dd = 0; dd < 64; ++dd) dot += qls[i][dd] * kls[j][dd];
    ee[i][j] = __expf(dot * SCALE);   // logits tiny: shift-free softmax safe
  }
  __syncthreads();
  if (tid < 64) {
    int i = tid >> 3, j = tid & 7;
    float ssum = 0.f;
#pragma unroll
    for (int jj = 0; jj < 8; ++jj) ssum += ee[i][jj];
    ws[K2_OFF + hb * 64 + tid] = ee[i][j] / ssum;
  }
  if (tid < 8) {
    float cs = 0.f;
    for (int ii = 0; ii < 8; ++ii) {
      float ssum = 0.f;
#pragma unroll
      for (int jj = 0; jj < 8; ++jj) ssum += ee[ii][jj];
      cs += ee[ii][tid] / ssum;
    }
    ws[CS_OFF + hb * 8 + tid] = cs;
  }
}

// ---------------------------------------------------------------------------
// 4. pinv (Newton-Schulz, global max over all 512 colsums) fused with
//    k3v reduce + W2 = pinv @ (k3v/den).  One 512-thr block per head.
// ---------------------------------------------------------------------------
__global__ __launch_bounds__(512) void pinvw2_kernel(float* __restrict__ ws) {
  int hb = blockIdx.x, tid = threadIdx.x;
  __shared__ float k3vs[8][68];
  __shared__ float K[8][9], V[8][9], X[8][9], Y[8][9];
  __shared__ float smax;
  int m = tid >> 6, d = tid & 63;
  float s = 0.f, den = 0.f;
  for (int c = 0; c < 64; ++c) {
    s += ws[PA_OFF + (((size_t)hb * 64 + c) * 8 + m) * 64 + d];
    den += ws[PD_OFF + ((size_t)hb * 64 + c) * 8 + m];
  }
  k3vs[m][d] = s / den;
  if (tid < 64) {
    float mx = 0.f;
    for (int t = 0; t < 8; ++t) mx = fmaxf(mx, ws[CS_OFF + t * 64 + tid]);
    for (int off = 32; off; off >>= 1) mx = fmaxf(mx, __shfl_xor(mx, off, 64));
    if (tid == 0) smax = mx;
  }
  int i = (tid >> 3) & 7, j = tid & 7;
  if (tid < 64) K[i][j] = ws[K2_OFF + hb * 64 + tid];
  __syncthreads();
  if (tid < 64) V[i][j] = K[j][i] * (1.f / smax);   // (1/max) * K^T
  __syncthreads();
  for (int it = 0; it < 6; ++it) {
    float x = 0.f;
    if (tid < 64) {
      for (int kk = 0; kk < 8; ++kk) x += K[i][kk] * V[kk][j];
      X[i][j] = x;
    }
    __syncthreads();
    float bm = 0.f;
    if (tid < 64) {
      for (int kk = 0; kk < 8; ++kk) bm += X[i][kk] * X[kk][j];
      bm = 7.f * x - bm;
      Y[i][j] = bm;
    }
    __syncthreads();
    float dm = 0.f;
    if (tid < 64) {
      for (int kk = 0; kk < 8; ++kk) dm += X[i][kk] * Y[kk][j];
      dm = 15.f * x - dm;
    }
    __syncthreads();
    if (tid < 64) Y[i][j] = dm;
    __syncthreads();
    float vd = 0.f;
    if (tid < 64) {
      for (int kk = 0; kk < 8; ++kk) vd += V[i][kk] * Y[kk][j];
      vd = 0.25f * (13.f * V[i][j] - vd);
    }
    __syncthreads();
    if (tid < 64) V[i][j] = vd;
    __syncthreads();
  }
  float o = 0.f;
#pragma unroll
  for (int jj = 0; jj < 8; ++jj) o += V[m][jj] * k3vs[jj][d];
  ws[W2_OFF + hb * 512 + tid] = o;
}

// ---------------------------------------------------------------------------
// 5. Output: barrier-free wave-private streaming.  Wave = 64 contiguous
//    tokens (4 x 16-token tiles).  klrow in VGPRs; W2 in private LDS.
//    p = exp(q.k_l*scale); out = (p/Σp) @ W2.  1 KB coalesced stores.
// ---------------------------------------------------------------------------
__global__ __launch_bounds__(256) void out_kernel(
    const float* __restrict__ q, float* __restrict__ out,
    const float* __restrict__ ws) {
  int tid = threadIdx.x;
  int w = tid >> 6, lane = tid & 63;
  int gw = blockIdx.x * 4 + w;            // 0..4095, 64 tokens each
  int hb = gw >> 6;
  __shared__ float qt_all[4][16][68];
  __shared__ float pl_all[4][16][9];
  __shared__ float w2_all[4][8][68];
  float (*qt)[68] = qt_all[w];
  float (*pl)[9]  = pl_all[w];
  float (*w2)[68] = w2_all[w];

  int m = lane & 7;
  float4 klrow[16];
#pragma unroll
  for (int d4 = 0; d4 < 16; ++d4)
    klrow[d4] = ((const float4*)(ws + KL_OFF))[hb * 128 + m * 16 + d4];
#pragma unroll
  for (int i = 0; i < 2; ++i) {
    int f4 = i * 64 + lane;
    float4 y = ((const float4*)(ws + W2_OFF))[hb * 128 + f4];
    *(float4*)&w2[f4 >> 4][(f4 & 15) * 4] = y;
  }

  size_t base4 = (size_t)gw * 1024;       // 64 tokens x 16 float4
  const float4* q4 = (const float4*)q + base4;
  float4* o4 = (float4*)out + base4;
  float4 buf[2][4];
#pragma unroll
  for (int i = 0; i < 4; ++i) buf[0][i] = q4[i * 64 + lane];

#pragma unroll
  for (int tile = 0; tile < 4; ++tile) {
    int cur = tile & 1;
    if (tile < 3) {
#pragma unroll
      for (int i = 0; i < 4; ++i)
        buf[cur ^ 1][i] = q4[(tile + 1) * 256 + i * 64 + lane];
    }
#pragma unroll
    for (int i = 0; i < 4; ++i) {
      int f4 = i * 64 + lane;
      *(float4*)&qt[f4 >> 4][(f4 & 15) * 4] = buf[cur][i];
    }
    WAVE_BAR();
#pragma unroll
    for (int rep = 0; rep < 2; ++rep) {
      int t = rep * 8 + (lane >> 3);
      const float4* qr = (const float4*)&qt[t][0];
      float dot = 0.f;
#pragma unroll
      for (int d4 = 0; d4 < 16; ++d4) {
        float4 a = qr[d4];
        dot += a.x * klrow[d4].x + a.y * klrow[d4].y +
               a.z * klrow[d4].z + a.w * klrow[d4].w;
      }
      pl[t][m] = __expf(dot * SCALE);     // logits tiny: no max needed
    }
    WAVE_BAR();
#pragma unroll
    for (int i = 0; i < 4; ++i) {
      int t = i * 4 + (lane >> 4);
      int qd = lane & 15;
      float p0 = pl[t][0], p1 = pl[t][1], p2 = pl[t][2], p3 = pl[t][3];
      float p4 = pl[t][4], p5 = pl[t][5], p6 = pl[t][6], p7 = pl[t][7];
      float inv = 1.f / (p0 + p1 + p2 + p3 + p4 + p5 + p6 + p7);
      float4 acc = make_float4(0.f, 0.f, 0.f, 0.f);
      float pm[8] = {p0, p1, p2, p3, p4, p5, p6, p7};
#pragma unroll
      for (int m2 = 0; m2 < 8; ++m2) {
        float wgt = pm[m2] * inv;
        float4 wv = *(const float4*)&w2[m2][qd * 4];
        acc.x += wgt * wv.x; acc.y += wgt * wv.y;
        acc.z += wgt * wv.z; acc.w += wgt * wv.w;
      }
      o4[tile * 256 + i * 64 + lane] = acc;   // 1 KB coalesced store
    }
    WAVE_BAR();
  }
}

// ---------------------------------------------------------------------------
extern "C" void kernel_launch(void* const* d_in, const int* in_sizes, int n_in,
                              void* d_out, int out_size, void* d_ws, size_t ws_size,
                              hipStream_t stream) {
  const float* q = (const float*)d_in[0];
  const float* k = (const float*)d_in[1];
  const float* v = (const float*)d_in[2];
  float* out = (float*)d_out;
  float* ws = (float*)d_ws;

  qsum_kernel<<<512, 256, 0, stream>>>(q, ws);
  kvpass_kernel<<<1024, 256, 0, stream>>>(k, v, ws);
  prepk_kernel<<<NHEADS, 512, 0, stream>>>(ws);
  pinvw2_kernel<<<NHEADS, 512, 0, stream>>>(ws);
  out_kernel<<<1024, 256, 0, stream>>>(q, out, ws);
}